// Round 18
// baseline (290.049 us; speedup 1.0000x reference)
//
#include <hip/hip_runtime.h>
#include <stdint.h>

// Problem constants
#define BB 8
#define CC 16
#define HH 512
#define WW 512
#define HW (HH * WW)          // 262144
#define NPIX (BB * HW)        // 2097152

// Binning: 8x8 output tiles, one WAVE per bin. Pixels whose 2x2 footprint
// crosses a tile edge emit duplicate records into each overlapped bin
// (avg x1.27) -> every bin owns its core exactly; NO halo merge pass.
// One cursor per bin, CAP=144 (mean 81, sigma ~9 -> 7 sigma). Overflow spills
// to a global buffer fixed up by k_fixup with exact atomics.
#define TS 8
#define TI 64
#define TJ 64
#define NBINS (BB * TI * TJ)  // 32768
#define CAP 144
#define OCAP 8192
// Accumulator: 10x10 cells/channel; rows/cols 0 and 9 are TRASH (out-of-tile
// taps land there, never read). CSTRIDE=100 -> taps add {0,1,10,11} ->
// exactly 2 lanes/bank (free, m136).
#define CSTRIDE 100

__device__ __forceinline__ uint32_t bf16_rne(float f) {
    uint32_t u = __float_as_uint(f);
    return (u + 0x7fffu + ((u >> 16) & 1u)) >> 16;
}

// Shared decode: matches reference rounding exactly (round-0 notes).
struct Dec { int oi0, oj0; float ai, aj; };
__device__ __forceinline__ Dec decode(float gx, float gy) {
    float gi = ((gx + 1.0f) * 0.5f) * (float)HH + 1.0f;
    float gj = ((gy + 1.0f) * 0.5f) * (float)WW + 1.0f;
    gi = fminf(fmaxf(gi, 0.0f), (float)(HH + 1));
    gj = fminf(fmaxf(gj, 0.0f), (float)(WW + 1));
    int fi = (int)gi, fj = (int)gj;     // >=1 -> trunc == floor
    Dec d;
    d.ai = gi - (float)fi;              // exact
    d.aj = gj - (float)fj;
    d.oi0 = fi - 1;                     // [0,512]
    d.oj0 = fj - 1;
    return d;
}

// ---- Phase 1: scatter 32B self-contained records ---------------------------
// counts[] zeroed by hipMemsetAsync; slot = bin*CAP + count.
// Record (8 dwords): d0=wpack, d1=scale_bf16<<16|s10, d2..d5=16x int8, d6,d7 pad.
// Written pair-cooperatively (lanes 2k,2k+1).
__global__ __launch_bounds__(256) void k_scatter(const float* __restrict__ x,
                                                 const float2* __restrict__ grid,
                                                 unsigned* __restrict__ counts,
                                                 uint4* __restrict__ recs,
                                                 uint2* __restrict__ obuf,
                                                 unsigned* __restrict__ ocur) {
    __shared__ uint32_t sPay[256][6];      // wpack, ybase, pay0..3
    __shared__ uint32_t sList[1024][2];    // slot, (tid<<8)|s10
    __shared__ unsigned nList;
    int tid = threadIdx.x;
    if (tid == 0) nList = 0;
    __syncthreads();

    int idx = blockIdx.x * 256 + tid;
    float2 g = grid[idx];
    int b = idx >> 18;
    Dec d = decode(g.x, g.y);
    bool valid = (d.oi0 < HH) && (d.oj0 < WW);

    if (valid) {
        const float* xp = x + (size_t)b * CC * HW + (idx & (HW - 1));
        float v[16];
#pragma unroll
        for (int c = 0; c < 16; ++c) v[c] = xp[c * HW];
        float m = 0.0f;
#pragma unroll
        for (int c = 0; c < 16; ++c) m = fmaxf(m, fabsf(v[c]));
        unsigned sbits = bf16_rne(m * (1.0f / 127.0f));
        float scale = __uint_as_float(sbits << 16);
        float inv = (scale > 0.0f) ? (1.0f / scale) : 0.0f;
#pragma unroll
        for (int w = 0; w < 4; ++w) {
            uint32_t dv = 0;
#pragma unroll
            for (int k = 0; k < 4; ++k) {
                float qf = fminf(fmaxf(rintf(v[w * 4 + k] * inv), -127.0f), 127.0f);
                dv |= ((uint32_t)(int)qf & 255u) << (k * 8);
            }
            sPay[tid][2 + w] = dv;
        }
        float wi0 = 1.0f - d.ai, wi1 = d.ai;
        float wj0 = 1.0f - d.aj, wj1 = d.aj;
        unsigned q00 = (unsigned)fmaf(wi0 * wj0, 255.0f, 0.5f);
        unsigned q01 = (unsigned)fmaf(wi0 * wj1, 255.0f, 0.5f);
        unsigned q10 = (unsigned)fmaf(wi1 * wj0, 255.0f, 0.5f);
        unsigned q11 = (unsigned)fmaf(wi1 * wj1, 255.0f, 0.5f);
        sPay[tid][0] = q00 | (q01 << 8) | (q10 << 16) | (q11 << 24);
        sPay[tid][1] = sbits << 16;

        int bI = d.oi0 >> 3, bJ = d.oj0 >> 3;
        unsigned si = (unsigned)(d.oi0 & 7) + 1;   // 1..8
        unsigned sj = (unsigned)(d.oj0 & 7) + 1;
        bool vr = (si == 8) && (d.oi0 != HH - 1);
        bool vc = (sj == 8) && (d.oj0 != WW - 1);
        auto emit = [&](int bi, int bj, unsigned s10) {
            unsigned bin = (unsigned)(((b * TI + bi) << 6) + bj);
            unsigned cnt = atomicAdd(&counts[bin], 1u);
            if (cnt < CAP) {
                unsigned e = atomicAdd(&nList, 1u);
                sList[e][0] = bin * CAP + cnt;
                sList[e][1] = ((unsigned)tid << 8) | s10;
            } else {
                unsigned o = atomicAdd(ocur, 1u);
                if (o < OCAP) obuf[o] = make_uint2((unsigned)idx, (bin << 7) | s10);
            }
        };
        emit(bI, bJ, si * 10 + sj);
        if (vr) emit(bI + 1, bJ, sj);              // si = 0
        if (vc) emit(bI, bJ + 1, si * 10);         // sj = 0
        if (vr && vc) emit(bI + 1, bJ + 1, 0);
    }
    __syncthreads();

    // Pair-cooperative write: entry k by lanes 2k,2k+1.
    unsigned n = nList;
    int h = tid & 1;
    for (unsigned base = 0; base < n; base += 128) {
        unsigned k = base + ((unsigned)tid >> 1);
        if (k < n) {
            unsigned slot = sList[k][0];
            unsigned info = sList[k][1];
            unsigned src = info >> 8, s10 = info & 127u;
            uint4 half;
            if (h == 0) {
                half = make_uint4(sPay[src][0], sPay[src][1] | s10,
                                  sPay[src][2], sPay[src][3]);
            } else {
                half = make_uint4(sPay[src][4], sPay[src][5], 0u, 0u);
            }
            recs[(size_t)slot * 2 + h] = half;
        }
    }
}

// ---- Phase 2: one wave per bin; register-resident record chunks ------------
// Round-17 accum was DS-pipe bound (~4.3 DS/record: staging + uniform reads +
// RMW). Now: the coalesced 1KB chunk load already puts record r in lanes
// 2r/2r+1's VGPRs -> extract meta/payload with readlane (compile-time lane
// index, unrolled) + cndmask select. DS = 2/record (just the acc RMW).
__global__ __launch_bounds__(256, 6) void k_accum(const uint4* __restrict__ recs4,
                                                  const unsigned* __restrict__ counts,
                                                  float* __restrict__ out) {
    __shared__ float acc[4][CC * CSTRIDE];    // 4 x 6400 B = 25.6 KB
    int wid = threadIdx.x >> 6;
    int lane = threadIdx.x & 63;
    int bin = blockIdx.x * 4 + wid;
    float* A = acc[wid];

    for (int k = lane; k < CC * CSTRIDE; k += 64) A[k] = 0.0f;
    // wave-private acc; same-wave DS ops are serviced in order (no barrier).

    unsigned n = (unsigned)__builtin_amdgcn_readfirstlane((int)counts[bin]);
    if (n > CAP) n = CAP;

    int ch = lane >> 2, tap = lane & 3;
    int wsh = tap << 3;                          // weight byte shift
    int ssh = 24 - ((ch & 3) << 3);              // payload byte sign-extend shift
    int di = tap >> 1, dj = tap & 1;
    int laneconst = ch * CSTRIDE + di * 10 + dj;
    bool sel1 = (ch >> 2) & 1;                   // wordsel bit0
    bool sel2 = (ch >> 2) & 2;                   // wordsel bit1

    const uint4* rp = recs4 + (size_t)bin * CAP * 2;   // 2 uint4 per record

    for (unsigned it = 0; it < n; it += 32) {
        uint4 dat = rp[(size_t)it * 2 + lane];   // coalesced 1KB chunk
        unsigned rem = n - it;                   // valid records this chunk
#pragma unroll
        for (int r = 0; r < 32; ++r) {
            unsigned w0 = __builtin_amdgcn_readlane(dat.x, 2 * r);      // wpack
            unsigned w1 = __builtin_amdgcn_readlane(dat.y, 2 * r);      // scale|s10
            unsigned p0 = __builtin_amdgcn_readlane(dat.z, 2 * r);
            unsigned p1 = __builtin_amdgcn_readlane(dat.w, 2 * r);
            unsigned p2 = __builtin_amdgcn_readlane(dat.x, 2 * r + 1);
            unsigned p3 = __builtin_amdgcn_readlane(dat.y, 2 * r + 1);
            bool ok = (unsigned)r < rem;                                // uniform
            unsigned lo = sel1 ? p1 : p0;
            unsigned hi = sel1 ? p3 : p2;
            unsigned vword = sel2 ? hi : lo;
            int s10 = ok ? (int)(w1 & 0x7Fu) : 0;     // mask garbage index
            float scale = __uint_as_float(w1 & 0xFFFF0000u);
            int q = ((int)(vword << ssh)) >> 24;      // sext byte
            float wb = (float)((w0 >> wsh) & 255u);
            float contrib = ((float)q * scale) * wb;
            contrib = ok ? contrib : 0.0f;            // after mul: kills NaN
            A[laneconst + s10] += contrib;            // 1/255 deferred
        }
    }

    // Core 8x8 writeback — exclusive owner, covers ALL out cells, coalesced.
    int tj = bin & 63, ti = (bin >> 6) & 63, b = bin >> 12;
    int gi0 = ti * TS, gj0 = tj * TS;
    int row = lane >> 3, col = lane & 7;
    for (int c = 0; c < CC; ++c) {
        float v = A[c * CSTRIDE + (row + 1) * 10 + (col + 1)] * (1.0f / 255.0f);
        out[((size_t)(b * CC + c) * HH + gi0 + row) * WW + gj0 + col] = v;
    }
}

// ---- Phase 3: fixup — replay overflowed emits with exact fp32 atomics ------
__global__ __launch_bounds__(256) void k_fixup(const float* __restrict__ x,
                                               const float2* __restrict__ grid,
                                               const uint2* __restrict__ obuf,
                                               const unsigned* __restrict__ ocur,
                                               float* __restrict__ out) {
    unsigned n = *ocur;
    if (n > OCAP) n = OCAP;
    for (unsigned i = blockIdx.x * 256 + threadIdx.x; i < n * 16; i += gridDim.x * 256) {
        unsigned e = i >> 4;
        int ch = (int)(i & 15u);
        uint2 rec = obuf[e];
        unsigned idx = rec.x;
        unsigned bin = rec.y >> 7, s10 = rec.y & 127u;
        int b = (int)(idx >> 18);
        float2 g = grid[idx];
        Dec d = decode(g.x, g.y);
        float v = x[(size_t)b * CC * HW + (size_t)ch * HW + (idx & (HW - 1))];
        int tj = (int)(bin & 63), ti = (int)((bin >> 6) & 63);
        int gi0 = ti * TS, gj0 = tj * TS;
        int si = (int)(s10 / 10), sj = (int)(s10 % 10);
        float wi0 = 1.0f - d.ai, wj0 = 1.0f - d.aj;
        float wt[2][2] = {{wi0 * wj0, wi0 * d.aj}, {d.ai * wj0, d.ai * d.aj}};
#pragma unroll
        for (int dd = 0; dd < 4; ++dd) {
            int dI = dd >> 1, dJ = dd & 1;
            int ri = si + dI, rj = sj + dJ;
            if (ri >= 1 && ri <= 8 && rj >= 1 && rj <= 8) {
                float* o = &out[((size_t)(b * CC + ch) * HH + gi0 + ri - 1) * WW + gj0 + rj - 1];
                unsafeAtomicAdd(o, v * wt[dI][dJ]);
            }
        }
    }
}

// ---- Fallback: direct scattered atomics ------------------------------------
__global__ __launch_bounds__(256) void splat_kernel(const float* __restrict__ x,
                                                    const float* __restrict__ grid,
                                                    float* __restrict__ out) {
    int idx = blockIdx.x * 256 + threadIdx.x;
    int j = idx & (WW - 1);
    int i = (idx >> 9) & (HH - 1);
    int b = idx >> 18;
    float2 g2 = reinterpret_cast<const float2*>(grid)[idx];
    float gi = ((g2.x + 1.0f) * 0.5f) * (float)HH + 1.0f;
    float gj = ((g2.y + 1.0f) * 0.5f) * (float)WW + 1.0f;
    gi = fminf(fmaxf(gi, 0.0f), (float)(HH + 1));
    gj = fminf(fmaxf(gj, 0.0f), (float)(WW + 1));
    int fi = (int)gi, fj = (int)gj;
    float ai = gi - (float)fi, aj = gj - (float)fj;
    float wi0 = 1.0f - ai, wj0 = 1.0f - aj;
    float w00 = wi0 * wj0, w01 = wi0 * aj, w10 = ai * wj0, w11 = ai * aj;
    int oi0 = fi - 1, oj0 = fj - 1;
    bool vi0 = (oi0 < HH), vi1 = (fi < HH), vj0 = (oj0 < WW), vj1 = (fj < WW);
    const float* xp = x + (size_t)b * CC * HW + i * WW + j;
    float* op = out + (size_t)b * CC * HW + oi0 * WW + oj0;
#pragma unroll
    for (int ch = 0; ch < CC; ++ch) {
        float v = xp[ch * HW];
        float* o = op + ch * HW;
        if (vi0 & vj0) unsafeAtomicAdd(o, v * w00);
        if (vi0 & vj1) unsafeAtomicAdd(o + 1, v * w01);
        if (vi1 & vj0) unsafeAtomicAdd(o + WW, v * w10);
        if (vi1 & vj1) unsafeAtomicAdd(o + WW + 1, v * w11);
    }
}

extern "C" void kernel_launch(void* const* d_in, const int* in_sizes, int n_in,
                              void* d_out, int out_size, void* d_ws, size_t ws_size,
                              hipStream_t stream) {
    const float* x = (const float*)d_in[0];
    const float* grid = (const float*)d_in[1];
    float* out = (float*)d_out;

    const size_t nslots = (size_t)NBINS * CAP;      // 4,718,592
    const size_t recs_bytes = nslots * 32;          // 151.0 MB
    const size_t cnt_bytes  = (size_t)NBINS * 4;    // 128 KB
    const size_t obuf_bytes = (size_t)OCAP * 8;     // 64 KB
    const size_t need = recs_bytes + cnt_bytes + 64 + obuf_bytes;

    if (ws_size < need) {
        hipMemsetAsync(out, 0, (size_t)out_size * sizeof(float), stream);
        splat_kernel<<<NPIX / 256, 256, 0, stream>>>(x, grid, out);
        return;
    }

    char* ws = (char*)d_ws;
    uint4* recs       = (uint4*)ws;                 ws += recs_bytes;
    unsigned* counts  = (unsigned*)ws;              ws += cnt_bytes;
    unsigned* ocur    = (unsigned*)ws;              ws += 64;
    uint2* obuf       = (uint2*)ws;

    // counts + ocur contiguous: one memset covers both.
    hipMemsetAsync(counts, 0, cnt_bytes + 64, stream);

    const float2* grid2 = (const float2*)grid;
    k_scatter<<<NPIX / 256, 256, 0, stream>>>(x, grid2, counts, recs, obuf, ocur);
    k_accum<<<NBINS / 4, 256, 0, stream>>>(recs, counts, out);
    k_fixup<<<32, 256, 0, stream>>>(x, grid2, obuf, ocur, out);
}

// Round 20
// 241.352 us; speedup vs baseline: 1.2018x; 1.2018x over previous
//
#include <hip/hip_runtime.h>
#include <stdint.h>

// Problem constants
#define BB 8
#define CC 16
#define HH 512
#define WW 512
#define HW (HH * WW)          // 262144
#define NPIX (BB * HW)        // 2097152

// Binning: 8x8 output tiles, one WAVE per bin. Pixels whose 2x2 footprint
// crosses a tile edge emit duplicate records into each overlapped bin
// (avg x1.27) -> every bin owns its core exactly; NO halo merge pass.
// 2 sub-cursors per bin (sub = oi0&1), CAP_SUB=72; cursors PADDED to one per
// 32B sector (stride 8 dwords) to cut same-line atomic serialization.
// Overflow spills to a global buffer fixed up by k_fixup with exact atomics.
#define TS 8
#define TI 64
#define TJ 64
#define NBINS (BB * TI * TJ)  // 32768
#define NCOPY 2
#define NSUB (NBINS * NCOPY)  // 65536
#define CAP_SUB 72
#define CURSTRIDE 8           // dwords between cursors (32B sector padding)
#define OCAP 8192
// Accumulator: 10x10 cells/channel; rows/cols 0 and 9 are TRASH. CSTRIDE=100
// -> taps add {0,1,10,11} -> exactly 2 lanes/bank (free, m136).
#define CSTRIDE 100

__device__ __forceinline__ uint32_t bf16_rne(float f) {
    uint32_t u = __float_as_uint(f);
    return (u + 0x7fffu + ((u >> 16) & 1u)) >> 16;
}

// Shared decode: matches reference rounding exactly (round-0 notes).
struct Dec { int oi0, oj0; float ai, aj; };
__device__ __forceinline__ Dec decode(float gx, float gy) {
    float gi = ((gx + 1.0f) * 0.5f) * (float)HH + 1.0f;
    float gj = ((gy + 1.0f) * 0.5f) * (float)WW + 1.0f;
    gi = fminf(fmaxf(gi, 0.0f), (float)(HH + 1));
    gj = fminf(fmaxf(gj, 0.0f), (float)(WW + 1));
    int fi = (int)gi, fj = (int)gj;     // >=1 -> trunc == floor
    Dec d;
    d.ai = gi - (float)fi;              // exact
    d.aj = gj - (float)fj;
    d.oi0 = fi - 1;                     // [0,512]
    d.oj0 = fj - 1;
    return d;
}

// ---- Phase 1: scatter 32B self-contained records ---------------------------
// counts[] zeroed by hipMemsetAsync; slot = sidx*CAP_SUB + count.
// Record (8 dwords): d0=wpack, d1=scale_bf16<<16|s10, d2..d5=16x int8, pad.
// Written PAIR-COOPERATIVELY (lanes 2k,2k+1 -> one 32B sector, round 16).
// (Round-17 structure verbatim; round-19's wave-aggregated allocation crashed
// and is reverted. Only change: CURSTRIDE cursor padding.)
__global__ __launch_bounds__(256) void k_scatter(const float* __restrict__ x,
                                                 const float2* __restrict__ grid,
                                                 unsigned* __restrict__ counts,
                                                 uint4* __restrict__ recs,
                                                 uint2* __restrict__ obuf,
                                                 unsigned* __restrict__ ocur) {
    __shared__ uint32_t sPay[256][6];      // wpack, ybase, pay0..3
    __shared__ uint32_t sList[1024][2];    // slot, (tid<<8)|s10
    __shared__ unsigned nList;
    int tid = threadIdx.x;
    if (tid == 0) nList = 0;
    __syncthreads();

    int idx = blockIdx.x * 256 + tid;
    float2 g = grid[idx];
    int b = idx >> 18;
    Dec d = decode(g.x, g.y);
    bool valid = (d.oi0 < HH) && (d.oj0 < WW);

    if (valid) {
        const float* xp = x + (size_t)b * CC * HW + (idx & (HW - 1));
        float v[16];
#pragma unroll
        for (int c = 0; c < 16; ++c) v[c] = xp[c * HW];
        float m = 0.0f;
#pragma unroll
        for (int c = 0; c < 16; ++c) m = fmaxf(m, fabsf(v[c]));
        unsigned sbits = bf16_rne(m * (1.0f / 127.0f));
        float scale = __uint_as_float(sbits << 16);
        float inv = (scale > 0.0f) ? (1.0f / scale) : 0.0f;
#pragma unroll
        for (int w = 0; w < 4; ++w) {
            uint32_t dv = 0;
#pragma unroll
            for (int k = 0; k < 4; ++k) {
                float qf = fminf(fmaxf(rintf(v[w * 4 + k] * inv), -127.0f), 127.0f);
                dv |= ((uint32_t)(int)qf & 255u) << (k * 8);
            }
            sPay[tid][2 + w] = dv;
        }
        float wi0 = 1.0f - d.ai, wi1 = d.ai;
        float wj0 = 1.0f - d.aj, wj1 = d.aj;
        unsigned q00 = (unsigned)fmaf(wi0 * wj0, 255.0f, 0.5f);
        unsigned q01 = (unsigned)fmaf(wi0 * wj1, 255.0f, 0.5f);
        unsigned q10 = (unsigned)fmaf(wi1 * wj0, 255.0f, 0.5f);
        unsigned q11 = (unsigned)fmaf(wi1 * wj1, 255.0f, 0.5f);
        sPay[tid][0] = q00 | (q01 << 8) | (q10 << 16) | (q11 << 24);
        sPay[tid][1] = sbits << 16;

        int bI = d.oi0 >> 3, bJ = d.oj0 >> 3;
        int sub = d.oi0 & 1;
        unsigned si = (unsigned)(d.oi0 & 7) + 1;   // 1..8
        unsigned sj = (unsigned)(d.oj0 & 7) + 1;
        bool vr = (si == 8) && (d.oi0 != HH - 1);
        bool vc = (sj == 8) && (d.oj0 != WW - 1);
        auto emit = [&](int bi, int bj, unsigned s10) {
            unsigned bin = (unsigned)(((b * TI + bi) << 6) + bj);
            unsigned sidx = bin * NCOPY + (unsigned)sub;
            unsigned cnt = atomicAdd(&counts[sidx * CURSTRIDE], 1u);
            if (cnt < CAP_SUB) {
                unsigned e = atomicAdd(&nList, 1u);
                sList[e][0] = sidx * CAP_SUB + cnt;
                sList[e][1] = ((unsigned)tid << 8) | s10;
            } else {
                unsigned o = atomicAdd(ocur, 1u);
                if (o < OCAP) obuf[o] = make_uint2((unsigned)idx, (bin << 7) | s10);
            }
        };
        emit(bI, bJ, si * 10 + sj);
        if (vr) emit(bI + 1, bJ, sj);              // si = 0
        if (vc) emit(bI, bJ + 1, si * 10);         // sj = 0
        if (vr && vc) emit(bI + 1, bJ + 1, 0);
    }
    __syncthreads();

    // Pair-cooperative write: entry k by lanes 2k,2k+1 -> one 32B sector.
    unsigned n = nList;
    int h = tid & 1;
    for (unsigned base = 0; base < n; base += 128) {
        unsigned k = base + ((unsigned)tid >> 1);
        if (k < n) {
            unsigned slot = sList[k][0];
            unsigned info = sList[k][1];
            unsigned src = info >> 8, s10 = info & 127u;
            uint4 half;
            if (h == 0) {
                half = make_uint4(sPay[src][0], sPay[src][1] | s10,
                                  sPay[src][2], sPay[src][3]);
            } else {
                half = make_uint4(sPay[src][4], sPay[src][5], 0u, 0u);
            }
            recs[(size_t)slot * 2 + h] = half;
        }
    }
}

// ---- Phase 2: one wave per bin, wave-private LDS tile + staging ------------
// (round-17 structure verbatim: coalesced 1KB chunk load -> wave-private LDS
// staging -> uniform ds_reads; no barriers, same-wave DS ops in order.)
__global__ __launch_bounds__(256, 5) void k_accum(const uint32_t* __restrict__ recs32,
                                                  const unsigned* __restrict__ counts,
                                                  float* __restrict__ out) {
    __shared__ float acc[4][CC * CSTRIDE];    // 4 x 6400 B
    __shared__ uint32_t stg[4][32 * 8];       // 4 x 1 KB record staging
    int wid = threadIdx.x >> 6;
    int lane = threadIdx.x & 63;
    int bin = blockIdx.x * 4 + wid;
    float* A = acc[wid];
    uint32_t* SG = stg[wid];

    for (int k = lane; k < CC * CSTRIDE; k += 64) A[k] = 0.0f;

    int ch = lane >> 2, tap = lane & 3;
    int wsh = tap << 3;                          // weight byte shift
    int ssh = 24 - ((ch & 3) << 3);              // payload byte sign-extend shift
    int di = tap >> 1, dj = tap & 1;
    int laneconst = ch * CSTRIDE + di * 10 + dj;
    int wordsel = ch >> 2;                       // payload dword 0..3

#pragma unroll
    for (int s = 0; s < NCOPY; ++s) {
        unsigned sidx = (unsigned)(bin * NCOPY + s);
        unsigned base = sidx * CAP_SUB;
        unsigned n = (unsigned)__builtin_amdgcn_readfirstlane(
                         (int)counts[sidx * CURSTRIDE]);
        if (n > CAP_SUB) n = CAP_SUB;
        const uint4* rp4 = (const uint4*)(recs32 + (size_t)base * 8);

        for (unsigned it = 0; it < n; it += 32) {
            unsigned cnt = n - it;
            if (cnt > 32) cnt = 32;
            uint4 dat = rp4[(size_t)it * 2 + lane];   // coalesced 1KB chunk
            ((uint4*)SG)[lane] = dat;                 // wave-private, in-order DS

            for (unsigned r0 = 0; r0 < cnt; r0 += 8) {
#pragma unroll
                for (int r = 0; r < 8; ++r) {
                    unsigned rr = r0 + (unsigned)r;
                    bool ok = rr < cnt;
                    unsigned w0 = SG[rr * 8];                 // uniform
                    unsigned w1 = SG[rr * 8 + 1];             // uniform
                    unsigned vword = SG[rr * 8 + 2 + wordsel];
                    int s10 = ok ? (int)(w1 & 0x7Fu) : 0;     // mask garbage idx
                    float scale = __uint_as_float(w1 & 0xFFFF0000u);
                    int q = ((int)(vword << ssh)) >> 24;      // sext byte
                    float wb = (float)((w0 >> wsh) & 255u);
                    float contrib = ((float)q * scale) * wb;
                    contrib = ok ? contrib : 0.0f;            // after mul: kills NaN
                    A[laneconst + s10] += contrib;            // 1/255 deferred
                }
            }
        }
    }

    // Core 8x8 writeback — exclusive owner, covers ALL out cells, coalesced.
    int tj = bin & 63, ti = (bin >> 6) & 63, b = bin >> 12;
    int gi0 = ti * TS, gj0 = tj * TS;
    int row = lane >> 3, col = lane & 7;
    for (int c = 0; c < CC; ++c) {
        float v = A[c * CSTRIDE + (row + 1) * 10 + (col + 1)] * (1.0f / 255.0f);
        out[((size_t)(b * CC + c) * HH + gi0 + row) * WW + gj0 + col] = v;
    }
}

// ---- Phase 3: fixup — replay overflowed emits with exact fp32 atomics ------
__global__ __launch_bounds__(256) void k_fixup(const float* __restrict__ x,
                                               const float2* __restrict__ grid,
                                               const uint2* __restrict__ obuf,
                                               const unsigned* __restrict__ ocur,
                                               float* __restrict__ out) {
    unsigned n = *ocur;
    if (n > OCAP) n = OCAP;
    for (unsigned i = blockIdx.x * 256 + threadIdx.x; i < n * 16; i += gridDim.x * 256) {
        unsigned e = i >> 4;
        int ch = (int)(i & 15u);
        uint2 rec = obuf[e];
        unsigned idx = rec.x;
        unsigned bin = rec.y >> 7, s10 = rec.y & 127u;
        int b = (int)(idx >> 18);
        float2 g = grid[idx];
        Dec d = decode(g.x, g.y);
        float v = x[(size_t)b * CC * HW + (size_t)ch * HW + (idx & (HW - 1))];
        int tj = (int)(bin & 63), ti = (int)((bin >> 6) & 63);
        int gi0 = ti * TS, gj0 = tj * TS;
        int si = (int)(s10 / 10), sj = (int)(s10 % 10);
        float wi0 = 1.0f - d.ai, wj0 = 1.0f - d.aj;
        float wt[2][2] = {{wi0 * wj0, wi0 * d.aj}, {d.ai * wj0, d.ai * d.aj}};
#pragma unroll
        for (int dd = 0; dd < 4; ++dd) {
            int dI = dd >> 1, dJ = dd & 1;
            int ri = si + dI, rj = sj + dJ;
            if (ri >= 1 && ri <= 8 && rj >= 1 && rj <= 8) {
                float* o = &out[((size_t)(b * CC + ch) * HH + gi0 + ri - 1) * WW + gj0 + rj - 1];
                unsafeAtomicAdd(o, v * wt[dI][dJ]);
            }
        }
    }
}

// ---- Fallback: direct scattered atomics ------------------------------------
__global__ __launch_bounds__(256) void splat_kernel(const float* __restrict__ x,
                                                    const float* __restrict__ grid,
                                                    float* __restrict__ out) {
    int idx = blockIdx.x * 256 + threadIdx.x;
    int j = idx & (WW - 1);
    int i = (idx >> 9) & (HH - 1);
    int b = idx >> 18;
    float2 g2 = reinterpret_cast<const float2*>(grid)[idx];
    float gi = ((g2.x + 1.0f) * 0.5f) * (float)HH + 1.0f;
    float gj = ((g2.y + 1.0f) * 0.5f) * (float)WW + 1.0f;
    gi = fminf(fmaxf(gi, 0.0f), (float)(HH + 1));
    gj = fminf(fmaxf(gj, 0.0f), (float)(WW + 1));
    int fi = (int)gi, fj = (int)gj;
    float ai = gi - (float)fi, aj = gj - (float)fj;
    float wi0 = 1.0f - ai, wj0 = 1.0f - aj;
    float w00 = wi0 * wj0, w01 = wi0 * aj, w10 = ai * wj0, w11 = ai * aj;
    int oi0 = fi - 1, oj0 = fj - 1;
    bool vi0 = (oi0 < HH), vi1 = (fi < HH), vj0 = (oj0 < WW), vj1 = (fj < WW);
    const float* xp = x + (size_t)b * CC * HW + i * WW + j;
    float* op = out + (size_t)b * CC * HW + oi0 * WW + oj0;
#pragma unroll
    for (int ch = 0; ch < CC; ++ch) {
        float v = xp[ch * HW];
        float* o = op + ch * HW;
        if (vi0 & vj0) unsafeAtomicAdd(o, v * w00);
        if (vi0 & vj1) unsafeAtomicAdd(o + 1, v * w01);
        if (vi1 & vj0) unsafeAtomicAdd(o + WW, v * w10);
        if (vi1 & vj1) unsafeAtomicAdd(o + WW + 1, v * w11);
    }
}

extern "C" void kernel_launch(void* const* d_in, const int* in_sizes, int n_in,
                              void* d_out, int out_size, void* d_ws, size_t ws_size,
                              hipStream_t stream) {
    const float* x = (const float*)d_in[0];
    const float* grid = (const float*)d_in[1];
    float* out = (float*)d_out;

    const size_t nslots = (size_t)NSUB * CAP_SUB;           // 4,718,592
    const size_t recs_bytes = nslots * 32;                  // 151.0 MB
    const size_t cnt_bytes  = (size_t)NSUB * CURSTRIDE * 4; // 2 MB (padded)
    const size_t obuf_bytes = (size_t)OCAP * 8;             // 64 KB
    const size_t need = recs_bytes + cnt_bytes + 64 + obuf_bytes;

    if (ws_size < need) {
        hipMemsetAsync(out, 0, (size_t)out_size * sizeof(float), stream);
        splat_kernel<<<NPIX / 256, 256, 0, stream>>>(x, grid, out);
        return;
    }

    char* ws = (char*)d_ws;
    uint4* recs       = (uint4*)ws;                 ws += recs_bytes;
    unsigned* counts  = (unsigned*)ws;              ws += cnt_bytes;
    unsigned* ocur    = (unsigned*)ws;              ws += 64;
    uint2* obuf       = (uint2*)ws;

    // counts + ocur contiguous: one memset covers both.
    hipMemsetAsync(counts, 0, cnt_bytes + 64, stream);

    const float2* grid2 = (const float2*)grid;
    k_scatter<<<NPIX / 256, 256, 0, stream>>>(x, grid2, counts, recs, obuf, ocur);
    k_accum<<<NBINS / 4, 256, 0, stream>>>((const uint32_t*)recs, counts, out);
    k_fixup<<<32, 256, 0, stream>>>(x, grid2, obuf, ocur, out);
}

// Round 21
// 226.357 us; speedup vs baseline: 1.2814x; 1.0662x over previous
//
#include <hip/hip_runtime.h>
#include <stdint.h>

// Problem constants
#define BB 8
#define CC 16
#define HH 512
#define WW 512
#define HW (HH * WW)          // 262144
#define NPIX (BB * HW)        // 2097152

// Binning: 8x8 output tiles, one WAVE per bin. Pixels whose 2x2 footprint
// crosses a tile edge emit duplicate records into each overlapped bin
// (avg x1.27) -> every bin owns its core exactly; NO halo merge pass.
// Fixed-capacity sub-bins: 2 counts per bin (sub = oi0&1), CAP_SUB=72
// (mean 40.3, sigma 6.4). Overflow spills to a global buffer fixed up by
// k_fixup with exact atomics -> capacity tail is harmless.
// ROUND-20 NOTE: this is round 17 verbatim — the measured optimum. Round 18
// (single cursor/bin), 19 (wave-aggregated alloc), 20 (sector-padded cursors)
// all regressed or crashed; cursor atomics are request-rate-bound, not
// line-bound, and the scattered record write is at the ~1.7-2 TB/s machinery
// ceiling. Both passes sit at their structural floors.
#define TS 8
#define TI 64
#define TJ 64
#define NBINS (BB * TI * TJ)  // 32768
#define NCOPY 2
#define NSUB (NBINS * NCOPY)  // 65536
#define CAP_SUB 72
#define OCAP 8192
// Accumulator: 10x10 cells/channel; rows/cols 0 and 9 are TRASH (out-of-tile
// taps land there, never read). CSTRIDE=100 -> taps add {0,1,10,11} ->
// exactly 2 lanes/bank (free, m136).
#define CSTRIDE 100

__device__ __forceinline__ uint32_t bf16_rne(float f) {
    uint32_t u = __float_as_uint(f);
    return (u + 0x7fffu + ((u >> 16) & 1u)) >> 16;
}

// Shared decode: matches reference rounding exactly (round-0 notes).
struct Dec { int oi0, oj0; float ai, aj; };
__device__ __forceinline__ Dec decode(float gx, float gy) {
    float gi = ((gx + 1.0f) * 0.5f) * (float)HH + 1.0f;
    float gj = ((gy + 1.0f) * 0.5f) * (float)WW + 1.0f;
    gi = fminf(fmaxf(gi, 0.0f), (float)(HH + 1));
    gj = fminf(fmaxf(gj, 0.0f), (float)(WW + 1));
    int fi = (int)gi, fj = (int)gj;     // >=1 -> trunc == floor
    Dec d;
    d.ai = gi - (float)fi;              // exact
    d.aj = gj - (float)fj;
    d.oi0 = fi - 1;                     // [0,512]
    d.oj0 = fj - 1;
    return d;
}

// ---- Phase 1: scatter 32B self-contained records ---------------------------
// counts[] zeroed by hipMemsetAsync; slot = sidx*CAP_SUB + count.
// Record (8 dwords): d0=wpack, d1=scale_bf16<<16|s10, d2..d5=16x int8, d6,d7 pad.
// Written PAIR-COOPERATIVELY (lanes 2k,2k+1 -> one 32B sector, round 16).
__global__ __launch_bounds__(256) void k_scatter(const float* __restrict__ x,
                                                 const float2* __restrict__ grid,
                                                 unsigned* __restrict__ counts,
                                                 uint4* __restrict__ recs,
                                                 uint2* __restrict__ obuf,
                                                 unsigned* __restrict__ ocur) {
    __shared__ uint32_t sPay[256][6];      // wpack, ybase, pay0..3
    __shared__ uint32_t sList[1024][2];    // slot, (tid<<8)|s10
    __shared__ unsigned nList;
    int tid = threadIdx.x;
    if (tid == 0) nList = 0;
    __syncthreads();

    int idx = blockIdx.x * 256 + tid;
    float2 g = grid[idx];
    int b = idx >> 18;
    Dec d = decode(g.x, g.y);
    bool valid = (d.oi0 < HH) && (d.oj0 < WW);

    if (valid) {
        const float* xp = x + (size_t)b * CC * HW + (idx & (HW - 1));
        float v[16];
#pragma unroll
        for (int c = 0; c < 16; ++c) v[c] = xp[c * HW];
        float m = 0.0f;
#pragma unroll
        for (int c = 0; c < 16; ++c) m = fmaxf(m, fabsf(v[c]));
        unsigned sbits = bf16_rne(m * (1.0f / 127.0f));
        float scale = __uint_as_float(sbits << 16);
        float inv = (scale > 0.0f) ? (1.0f / scale) : 0.0f;
#pragma unroll
        for (int w = 0; w < 4; ++w) {
            uint32_t dv = 0;
#pragma unroll
            for (int k = 0; k < 4; ++k) {
                float qf = fminf(fmaxf(rintf(v[w * 4 + k] * inv), -127.0f), 127.0f);
                dv |= ((uint32_t)(int)qf & 255u) << (k * 8);
            }
            sPay[tid][2 + w] = dv;
        }
        float wi0 = 1.0f - d.ai, wi1 = d.ai;
        float wj0 = 1.0f - d.aj, wj1 = d.aj;
        unsigned q00 = (unsigned)fmaf(wi0 * wj0, 255.0f, 0.5f);
        unsigned q01 = (unsigned)fmaf(wi0 * wj1, 255.0f, 0.5f);
        unsigned q10 = (unsigned)fmaf(wi1 * wj0, 255.0f, 0.5f);
        unsigned q11 = (unsigned)fmaf(wi1 * wj1, 255.0f, 0.5f);
        sPay[tid][0] = q00 | (q01 << 8) | (q10 << 16) | (q11 << 24);
        sPay[tid][1] = sbits << 16;

        int bI = d.oi0 >> 3, bJ = d.oj0 >> 3;
        int sub = d.oi0 & 1;
        unsigned si = (unsigned)(d.oi0 & 7) + 1;   // 1..8
        unsigned sj = (unsigned)(d.oj0 & 7) + 1;
        bool vr = (si == 8) && (d.oi0 != HH - 1);
        bool vc = (sj == 8) && (d.oj0 != WW - 1);
        auto emit = [&](int bi, int bj, unsigned s10) {
            unsigned bin = (unsigned)(((b * TI + bi) << 6) + bj);
            unsigned sidx = bin * NCOPY + (unsigned)sub;
            unsigned cnt = atomicAdd(&counts[sidx], 1u);
            if (cnt < CAP_SUB) {
                unsigned e = atomicAdd(&nList, 1u);
                sList[e][0] = sidx * CAP_SUB + cnt;
                sList[e][1] = ((unsigned)tid << 8) | s10;
            } else {
                unsigned o = atomicAdd(ocur, 1u);
                if (o < OCAP) obuf[o] = make_uint2((unsigned)idx, (bin << 7) | s10);
            }
        };
        emit(bI, bJ, si * 10 + sj);
        if (vr) emit(bI + 1, bJ, sj);              // si = 0
        if (vc) emit(bI, bJ + 1, si * 10);         // sj = 0
        if (vr && vc) emit(bI + 1, bJ + 1, 0);
    }
    __syncthreads();

    // Pair-cooperative write: entry k by lanes 2k,2k+1 -> one 32B sector.
    unsigned n = nList;
    int h = tid & 1;
    for (unsigned base = 0; base < n; base += 128) {
        unsigned k = base + ((unsigned)tid >> 1);
        if (k < n) {
            unsigned slot = sList[k][0];
            unsigned info = sList[k][1];
            unsigned src = info >> 8, s10 = info & 127u;
            uint4 half;
            if (h == 0) {
                half = make_uint4(sPay[src][0], sPay[src][1] | s10,
                                  sPay[src][2], sPay[src][3]);
            } else {
                half = make_uint4(sPay[src][4], sPay[src][5], 0u, 0u);
            }
            recs[(size_t)slot * 2 + h] = half;
        }
    }
}

// ---- Phase 2: one wave per bin, wave-private LDS tile + staging ------------
// Coalesced 1KB chunk load -> wave-private LDS staging -> uniform ds_reads;
// no barriers (same-wave DS ops are serviced in order).
__global__ __launch_bounds__(256, 5) void k_accum(const uint32_t* __restrict__ recs32,
                                                  const unsigned* __restrict__ counts,
                                                  float* __restrict__ out) {
    __shared__ float acc[4][CC * CSTRIDE];    // 4 x 6400 B
    __shared__ uint32_t stg[4][32 * 8];       // 4 x 1 KB record staging
    int wid = threadIdx.x >> 6;
    int lane = threadIdx.x & 63;
    int bin = blockIdx.x * 4 + wid;
    float* A = acc[wid];
    uint32_t* SG = stg[wid];

    for (int k = lane; k < CC * CSTRIDE; k += 64) A[k] = 0.0f;

    uint2 cur2 = ((const uint2*)counts)[bin];   // the bin's 2 sub-counts

    int ch = lane >> 2, tap = lane & 3;
    int wsh = tap << 3;                          // weight byte shift
    int ssh = 24 - ((ch & 3) << 3);              // payload byte sign-extend shift
    int di = tap >> 1, dj = tap & 1;
    int laneconst = ch * CSTRIDE + di * 10 + dj;
    int wordsel = ch >> 2;                       // payload dword 0..3

#pragma unroll
    for (int s = 0; s < NCOPY; ++s) {
        unsigned sidx = (unsigned)(bin * NCOPY + s);
        unsigned base = sidx * CAP_SUB;
        unsigned n = (unsigned)__builtin_amdgcn_readfirstlane(
                         (int)(s ? cur2.y : cur2.x));
        if (n > CAP_SUB) n = CAP_SUB;
        const uint4* rp4 = (const uint4*)(recs32 + (size_t)base * 8);

        for (unsigned it = 0; it < n; it += 32) {
            unsigned cnt = n - it;
            if (cnt > 32) cnt = 32;
            // Coalesced 1KB chunk load (reads past cursor stay in ws; ignored)
            uint4 dat = rp4[(size_t)it * 2 + lane];
            ((uint4*)SG)[lane] = dat;            // wave-private, in-order DS

            for (unsigned r0 = 0; r0 < cnt; r0 += 8) {
#pragma unroll
                for (int r = 0; r < 8; ++r) {
                    unsigned rr = r0 + (unsigned)r;
                    bool ok = rr < cnt;
                    unsigned w0 = SG[rr * 8];                 // uniform
                    unsigned w1 = SG[rr * 8 + 1];             // uniform
                    unsigned vword = SG[rr * 8 + 2 + wordsel];
                    int s10 = ok ? (int)(w1 & 0x7Fu) : 0;     // mask garbage idx
                    float scale = __uint_as_float(w1 & 0xFFFF0000u);
                    int q = ((int)(vword << ssh)) >> 24;      // sext byte
                    float wb = (float)((w0 >> wsh) & 255u);
                    float contrib = ((float)q * scale) * wb;
                    contrib = ok ? contrib : 0.0f;            // after mul: kills NaN
                    A[laneconst + s10] += contrib;            // 1/255 deferred
                }
            }
        }
    }

    // Core 8x8 writeback — exclusive owner, covers ALL out cells, coalesced.
    int tj = bin & 63, ti = (bin >> 6) & 63, b = bin >> 12;
    int gi0 = ti * TS, gj0 = tj * TS;
    int row = lane >> 3, col = lane & 7;
    for (int c = 0; c < CC; ++c) {
        float v = A[c * CSTRIDE + (row + 1) * 10 + (col + 1)] * (1.0f / 255.0f);
        out[((size_t)(b * CC + c) * HH + gi0 + row) * WW + gj0 + col] = v;
    }
}

// ---- Phase 3: fixup — replay overflowed emits with exact fp32 atomics ------
__global__ __launch_bounds__(256) void k_fixup(const float* __restrict__ x,
                                               const float2* __restrict__ grid,
                                               const uint2* __restrict__ obuf,
                                               const unsigned* __restrict__ ocur,
                                               float* __restrict__ out) {
    unsigned n = *ocur;
    if (n > OCAP) n = OCAP;
    for (unsigned i = blockIdx.x * 256 + threadIdx.x; i < n * 16; i += gridDim.x * 256) {
        unsigned e = i >> 4;
        int ch = (int)(i & 15u);
        uint2 rec = obuf[e];
        unsigned idx = rec.x;
        unsigned bin = rec.y >> 7, s10 = rec.y & 127u;
        int b = (int)(idx >> 18);
        float2 g = grid[idx];
        Dec d = decode(g.x, g.y);
        float v = x[(size_t)b * CC * HW + (size_t)ch * HW + (idx & (HW - 1))];
        int tj = (int)(bin & 63), ti = (int)((bin >> 6) & 63);
        int gi0 = ti * TS, gj0 = tj * TS;
        int si = (int)(s10 / 10), sj = (int)(s10 % 10);
        float wi0 = 1.0f - d.ai, wj0 = 1.0f - d.aj;
        float wt[2][2] = {{wi0 * wj0, wi0 * d.aj}, {d.ai * wj0, d.ai * d.aj}};
#pragma unroll
        for (int dd = 0; dd < 4; ++dd) {
            int dI = dd >> 1, dJ = dd & 1;
            int ri = si + dI, rj = sj + dJ;
            if (ri >= 1 && ri <= 8 && rj >= 1 && rj <= 8) {
                float* o = &out[((size_t)(b * CC + ch) * HH + gi0 + ri - 1) * WW + gj0 + rj - 1];
                unsafeAtomicAdd(o, v * wt[dI][dJ]);
            }
        }
    }
}

// ---- Fallback: direct scattered atomics ------------------------------------
__global__ __launch_bounds__(256) void splat_kernel(const float* __restrict__ x,
                                                    const float* __restrict__ grid,
                                                    float* __restrict__ out) {
    int idx = blockIdx.x * 256 + threadIdx.x;
    int j = idx & (WW - 1);
    int i = (idx >> 9) & (HH - 1);
    int b = idx >> 18;
    float2 g2 = reinterpret_cast<const float2*>(grid)[idx];
    float gi = ((g2.x + 1.0f) * 0.5f) * (float)HH + 1.0f;
    float gj = ((g2.y + 1.0f) * 0.5f) * (float)WW + 1.0f;
    gi = fminf(fmaxf(gi, 0.0f), (float)(HH + 1));
    gj = fminf(fmaxf(gj, 0.0f), (float)(WW + 1));
    int fi = (int)gi, fj = (int)gj;
    float ai = gi - (float)fi, aj = gj - (float)fj;
    float wi0 = 1.0f - ai, wj0 = 1.0f - aj;
    float w00 = wi0 * wj0, w01 = wi0 * aj, w10 = ai * wj0, w11 = ai * aj;
    int oi0 = fi - 1, oj0 = fj - 1;
    bool vi0 = (oi0 < HH), vi1 = (fi < HH), vj0 = (oj0 < WW), vj1 = (fj < WW);
    const float* xp = x + (size_t)b * CC * HW + i * WW + j;
    float* op = out + (size_t)b * CC * HW + oi0 * WW + oj0;
#pragma unroll
    for (int ch = 0; ch < CC; ++ch) {
        float v = xp[ch * HW];
        float* o = op + ch * HW;
        if (vi0 & vj0) unsafeAtomicAdd(o, v * w00);
        if (vi0 & vj1) unsafeAtomicAdd(o + 1, v * w01);
        if (vi1 & vj0) unsafeAtomicAdd(o + WW, v * w10);
        if (vi1 & vj1) unsafeAtomicAdd(o + WW + 1, v * w11);
    }
}

extern "C" void kernel_launch(void* const* d_in, const int* in_sizes, int n_in,
                              void* d_out, int out_size, void* d_ws, size_t ws_size,
                              hipStream_t stream) {
    const float* x = (const float*)d_in[0];
    const float* grid = (const float*)d_in[1];
    float* out = (float*)d_out;

    const size_t nslots = (size_t)NSUB * CAP_SUB;   // 4,718,592
    const size_t recs_bytes = nslots * 32;          // 151.0 MB
    const size_t cnt_bytes  = (size_t)NSUB * 4;     // 256 KB
    const size_t obuf_bytes = (size_t)OCAP * 8;     // 64 KB
    const size_t need = recs_bytes + cnt_bytes + 64 + obuf_bytes;

    if (ws_size < need) {
        hipMemsetAsync(out, 0, (size_t)out_size * sizeof(float), stream);
        splat_kernel<<<NPIX / 256, 256, 0, stream>>>(x, grid, out);
        return;
    }

    char* ws = (char*)d_ws;
    uint4* recs       = (uint4*)ws;                 ws += recs_bytes;
    unsigned* counts  = (unsigned*)ws;              ws += cnt_bytes;
    unsigned* ocur    = (unsigned*)ws;              ws += 64;
    uint2* obuf       = (uint2*)ws;

    // counts + ocur contiguous: one memset covers both.
    hipMemsetAsync(counts, 0, cnt_bytes + 64, stream);

    const float2* grid2 = (const float2*)grid;
    k_scatter<<<NPIX / 256, 256, 0, stream>>>(x, grid2, counts, recs, obuf, ocur);
    k_accum<<<NBINS / 4, 256, 0, stream>>>((const uint32_t*)recs, counts, out);
    k_fixup<<<32, 256, 0, stream>>>(x, grid2, obuf, ocur, out);
}